// Round 3
// baseline (366.758 us; speedup 1.0000x reference)
//
#include <hip/hip_runtime.h>
#include <hip/hip_bf16.h>
#include <cstdint>
#include <cstddef>

// YatAttention on MI355X (gfx950).
// B=2, L=2048, E=768, H=12, D=64. GEMMs in bf16 MFMA 16x16x32 (fp32 accum);
// score transform + softmax fp32.
// R3: k_attn computes S^T = K.Q^T (swap MFMA operands) so each lane owns 16
// scores of ONE query -> row reductions are 15 in-register ops + 2 shuffles
// (was 32 serial shuffles/tile). Split-K S=2.

typedef __bf16 bf16_t;
typedef __bf16 bf16x8 __attribute__((ext_vector_type(8)));
typedef __bf16 bf16x4 __attribute__((ext_vector_type(4)));
typedef float floatx4 __attribute__((ext_vector_type(4)));

#define DEVI static __device__ __forceinline__

#define Bc 2
#define Lc 2048
#define Ec 768
#define Hc 12
#define Dc 64
#define N3c 2304
#define Mc 4096
#define ROWSc (Bc * Hc * Lc)  // 49152

DEVI void glds16(const bf16_t* g, bf16_t* l) {
  __builtin_amdgcn_global_load_lds(
      (const __attribute__((address_space(1))) void*)g,
      (__attribute__((address_space(3))) void*)l, 16, 0, 0);
}

// ---------------- conversion kernels ----------------

__global__ __launch_bounds__(256) void k_cvt(const float* __restrict__ in,
                                             bf16_t* __restrict__ out, int n) {
  int i = (blockIdx.x * 256 + threadIdx.x) * 4;
  if (i >= n) return;
  float4 v = *(const float4*)(in + i);
  bf16x4 o;
  o[0] = (bf16_t)v.x; o[1] = (bf16_t)v.y; o[2] = (bf16_t)v.z; o[3] = (bf16_t)v.w;
  *(bf16x4*)(out + i) = o;
}

__global__ __launch_bounds__(256) void k_tc(const float* __restrict__ in,
                                            bf16_t* __restrict__ out, int R, int C) {
  __shared__ float tile[32][33];
  int c0 = blockIdx.x * 32, r0 = blockIdx.y * 32;
  int tx = threadIdx.x, ty = threadIdx.y;
  #pragma unroll
  for (int i = 0; i < 32; i += 8)
    tile[ty + i][tx] = in[(size_t)(r0 + ty + i) * C + c0 + tx];
  __syncthreads();
  #pragma unroll
  for (int i = 0; i < 32; i += 8)
    out[(size_t)(c0 + ty + i) * R + r0 + tx] = (bf16_t)tile[tx][ty + i];
}

// ---------------- GEMM core (m97 pattern) ----------------

DEVI void gemm_core(const bf16_t* __restrict__ A, const bf16_t* __restrict__ Bt,
                    bf16_t* lA, bf16_t* lB, int m0, int n0, floatx4 (&acc)[4][4]) {
  const int tid = threadIdx.x, wave = tid >> 6, lane = tid & 63;
  const int wm = (wave >> 1) * 64, wn = (wave & 1) * 64;
  const int lrow = lane >> 2, lseg = lane & 3;
  const int quad = lane >> 4, r16 = lane & 15;
  for (int kk = 0; kk < 768; kk += 32) {
    glds16(A  + (size_t)(m0 + wave * 32      + lrow) * 768 + kk + lseg * 8, lA + (wave * 32) * 32);
    glds16(A  + (size_t)(m0 + wave * 32 + 16 + lrow) * 768 + kk + lseg * 8, lA + (wave * 32 + 16) * 32);
    glds16(Bt + (size_t)(n0 + wave * 32      + lrow) * 768 + kk + lseg * 8, lB + (wave * 32) * 32);
    glds16(Bt + (size_t)(n0 + wave * 32 + 16 + lrow) * 768 + kk + lseg * 8, lB + (wave * 32 + 16) * 32);
    __syncthreads();
    bf16x8 af[4], bv[4];
    #pragma unroll
    for (int mi = 0; mi < 4; mi++)
      af[mi] = *(const bf16x8*)(lA + (wm + mi * 16 + r16) * 32 + quad * 8);
    #pragma unroll
    for (int ni = 0; ni < 4; ni++)
      bv[ni] = *(const bf16x8*)(lB + (wn + ni * 16 + r16) * 32 + quad * 8);
    #pragma unroll
    for (int mi = 0; mi < 4; mi++)
      #pragma unroll
      for (int ni = 0; ni < 4; ni++)
        acc[mi][ni] = __builtin_amdgcn_mfma_f32_16x16x32_bf16(af[mi], bv[ni], acc[mi][ni], 0, 0, 0);
    __syncthreads();
  }
}

__global__ __launch_bounds__(256) void k_gemm_qkv(
    const bf16_t* __restrict__ A, const bf16_t* __restrict__ Bt,
    const float* __restrict__ bias,
    bf16_t* __restrict__ Qo, bf16_t* __restrict__ Ko, bf16_t* __restrict__ Vo) {
  __shared__ bf16_t lA[128 * 32];
  __shared__ bf16_t lB[128 * 32];
  const int m0 = blockIdx.y * 128, n0 = blockIdx.x * 128;
  const int tid = threadIdx.x, wave = tid >> 6, lane = tid & 63;
  const int wm = (wave >> 1) * 64, wn = (wave & 1) * 64;
  const int quad = lane >> 4, r16 = lane & 15;
  floatx4 acc[4][4] = {};
  gemm_core(A, Bt, lA, lB, m0, n0, acc);

  const int sec = n0 / 768;
  bf16_t* dst = (sec == 0) ? Qo : ((sec == 1) ? Ko : Vo);
  #pragma unroll
  for (int ni = 0; ni < 4; ni++) {
    const int n = n0 + wn + ni * 16 + r16;
    const int nn = n - sec * 768;
    const int h = nn >> 6, d = nn & 63;
    const float bvs = bias[n];
    #pragma unroll
    for (int mi = 0; mi < 4; mi++) {
      #pragma unroll
      for (int reg = 0; reg < 4; reg++) {
        const int m = m0 + wm + mi * 16 + quad * 4 + reg;
        const int b = m >> 11, l = m & 2047;
        const float v = acc[mi][ni][reg] + bvs;
        dst[(((size_t)(b * Hc + h)) * Lc + l) * Dc + d] = (bf16_t)v;
      }
    }
  }
}

__global__ __launch_bounds__(256) void k_gemm_out(
    const bf16_t* __restrict__ A, const bf16_t* __restrict__ Bt,
    const float* __restrict__ bias, float* __restrict__ out) {
  __shared__ bf16_t lA[128 * 32];
  __shared__ bf16_t lB[128 * 32];
  const int m0 = blockIdx.y * 128, n0 = blockIdx.x * 128;
  const int tid = threadIdx.x, wave = tid >> 6, lane = tid & 63;
  const int wm = (wave >> 1) * 64, wn = (wave & 1) * 64;
  const int quad = lane >> 4, r16 = lane & 15;
  floatx4 acc[4][4] = {};
  gemm_core(A, Bt, lA, lB, m0, n0, acc);
  #pragma unroll
  for (int ni = 0; ni < 4; ni++) {
    const int n = n0 + wn + ni * 16 + r16;
    const float bvs = bias[n];
    #pragma unroll
    for (int mi = 0; mi < 4; mi++) {
      #pragma unroll
      for (int reg = 0; reg < 4; reg++) {
        const int m = m0 + wm + mi * 16 + quad * 4 + reg;
        out[(size_t)m * Ec + n] = acc[mi][ni][reg] + bvs;
      }
    }
  }
}

// ---------------- q_sq / k_sq ----------------
__global__ __launch_bounds__(256) void k_sq(const bf16_t* __restrict__ Q,
                                            const bf16_t* __restrict__ K,
                                            float* __restrict__ qsq, float* __restrict__ ksq) {
  const int row = blockIdx.x * 256 + threadIdx.x;
  const bf16x8* q = (const bf16x8*)(Q + (size_t)row * 64);
  const bf16x8* k = (const bf16x8*)(K + (size_t)row * 64);
  float sq = 0.f, sk = 0.f;
  #pragma unroll
  for (int c = 0; c < 8; c++) {
    bf16x8 vq = q[c], vk = k[c];
    #pragma unroll
    for (int j = 0; j < 8; j++) {
      float a = (float)vq[j]; sq += a * a;
      float b = (float)vk[j]; sk += b * b;
    }
  }
  qsq[row] = sq;
  ksq[row] = sk;
}

// ---------------- V transpose ----------------
__global__ __launch_bounds__(256) void k_vt(const bf16_t* __restrict__ V,
                                            bf16_t* __restrict__ VT) {
  __shared__ bf16_t t[64][72];
  const int gid = blockIdx.x;
  const int bh = gid >> 5, j0 = (gid & 31) * 64;
  const int tid = threadIdx.x;
  const bf16_t* Vh = V + ((size_t)bh * Lc) * Dc;
  bf16_t* VTh = VT + ((size_t)bh * Dc) * Lc;
  #pragma unroll
  for (int it = 0; it < 2; ++it) {
    int c = tid + it * 256;
    int j = c >> 3, seg = c & 7;
    *(bf16x8*)&t[j][seg * 8] = *(const bf16x8*)(Vh + (size_t)(j0 + j) * 64 + seg * 8);
  }
  __syncthreads();
  #pragma unroll
  for (int it = 0; it < 2; ++it) {
    int c = tid + it * 256;
    int d = c >> 3, jseg = c & 7;
    bf16x8 o;
    #pragma unroll
    for (int u = 0; u < 8; u++) o[u] = t[jseg * 8 + u][d];
    *(bf16x8*)(VTh + (size_t)d * Lc + j0 + jseg * 8) = o;
  }
}

// ---------------- flash attention (S^T form), split over keys ----------------
__global__ __launch_bounds__(256) void k_attn(
    const bf16_t* __restrict__ Q, const bf16_t* __restrict__ K,
    const bf16_t* __restrict__ VT, const float* __restrict__ qsq,
    const float* __restrict__ ksq, const int* __restrict__ mask,
    float* __restrict__ Op, float* __restrict__ Mp, float* __restrict__ Lp,
    int nS) {
  __shared__ bf16_t lP[4][16 * 72];
  const int gid = blockIdx.x;
  const int s = blockIdx.y;
  const int bh = gid >> 5, qt = gid & 31;
  const int b = bh / Hc;
  const int tid = threadIdx.x, wave = tid >> 6, lane = tid & 63;
  const int quad = lane >> 4, r16 = lane & 15;
  const int q0 = qt * 64 + wave * 16;
  const bf16_t* Qh = Q + ((size_t)bh * Lc) * Dc;
  const bf16_t* Kh = K + ((size_t)bh * Lc) * Dc;
  const bf16_t* VTh = VT + ((size_t)bh * Dc) * Lc;
  const float* qsqh = qsq + bh * Lc;
  const float* ksqh = ksq + bh * Lc;
  const int* maskb = mask + b * Lc;
  bf16_t* myP = &lP[wave][0];

  const int kt_lo = (32 * s) / nS * 64;
  const int kt_hi = (32 * (s + 1)) / nS * 64;

  // Q B-fragments (n = query = r16): rows q0+r16 of Q, D-chunks at quad*8.
  bf16x8 qf0 = *(const bf16x8*)(Qh + (size_t)(q0 + r16) * 64 + quad * 8);
  bf16x8 qf1 = *(const bf16x8*)(Qh + (size_t)(q0 + r16) * 64 + 32 + quad * 8);
  const float qs = qsqh[q0 + r16];  // this lane's query q^2
  float mi = -1e30f, li = 0.f;      // per-query (r16) online stats
  floatx4 of[4] = {};               // PV accum: row = query quad*4+reg, col=d

  for (int kt = kt_lo; kt < kt_hi; kt += 64) {
    floatx4 dot[4];
    float4 ks4[4];
    int4 mk4[4];
    #pragma unroll
    for (int c = 0; c < 4; c++) {
      const int krow = kt + c * 16 + r16;
      bf16x8 kf0 = *(const bf16x8*)(Kh + (size_t)krow * 64 + quad * 8);
      bf16x8 kf1 = *(const bf16x8*)(Kh + (size_t)krow * 64 + 32 + quad * 8);
      floatx4 a = {};
      // S^T: A = K (m = key), B = Q (n = query)
      a = __builtin_amdgcn_mfma_f32_16x16x32_bf16(kf0, qf0, a, 0, 0, 0);
      a = __builtin_amdgcn_mfma_f32_16x16x32_bf16(kf1, qf1, a, 0, 0, 0);
      dot[c] = a;
      ks4[c] = *(const float4*)(ksqh + kt + c * 16 + quad * 4);
      mk4[c] = *(const int4*)(maskb + kt + c * 16 + quad * 4);
    }
    // this lane: query r16, keys kt + c*16 + quad*4 + reg  (16 scores)
    float sv[4][4];
    float rmax = -1e30f;
    #pragma unroll
    for (int c = 0; c < 4; c++) {
      #pragma unroll
      for (int reg = 0; reg < 4; reg++) {
        const float dd = dot[c][reg];
        const float kss = ((const float*)&ks4[c])[reg];
        const int mk = ((const int*)&mk4[c])[reg];
        const float den = qs + kss - 2.f * dd + 1e-6f;
        float sc = dd * dd * __builtin_amdgcn_rcpf(den);
        sc = (mk == 1) ? sc : -1e30f;
        sv[c][reg] = sc;
        rmax = fmaxf(rmax, sc);
      }
    }
    rmax = fmaxf(rmax, __shfl_xor(rmax, 16));
    rmax = fmaxf(rmax, __shfl_xor(rmax, 32));
    const float mnew = fmaxf(mi, rmax);
    const float alpha = __expf(mi - mnew);
    // redistribute alpha[query] to of-row owners (row = quad*4+reg)
    float arow[4];
    #pragma unroll
    for (int reg = 0; reg < 4; reg++)
      arow[reg] = __int_as_float(__builtin_amdgcn_ds_bpermute(
          4 * ((quad << 4) | ((quad << 2) + reg)), __float_as_int(alpha)));
    float psum = 0.f;
    #pragma unroll
    for (int c = 0; c < 4; c++) {
      bf16x4 pk;
      #pragma unroll
      for (int reg = 0; reg < 4; reg++) {
        const int mk = ((const int*)&mk4[c])[reg];
        const float p = (mk == 1) ? __expf(sv[c][reg] - mnew) : 0.f;
        psum += p;
        pk[reg] = (bf16_t)p;
      }
      *(bf16x4*)(myP + r16 * 72 + c * 16 + quad * 4) = pk;  // P[query][key]
    }
    psum += __shfl_xor(psum, 16);
    psum += __shfl_xor(psum, 32);
    li = li * alpha + psum;
    mi = mnew;
    #pragma unroll
    for (int t4 = 0; t4 < 4; t4++) {
      #pragma unroll
      for (int reg = 0; reg < 4; reg++) of[t4][reg] *= arow[reg];
    }
    // PV: A = P (m=query, k=key), B = V^T (n=d)
    bf16x8 pf0 = *(const bf16x8*)(myP + r16 * 72 + quad * 8);
    bf16x8 pf1 = *(const bf16x8*)(myP + r16 * 72 + 32 + quad * 8);
    #pragma unroll
    for (int t4 = 0; t4 < 4; t4++) {
      bf16x8 vf0 = *(const bf16x8*)(VTh + (size_t)(t4 * 16 + r16) * Lc + kt + quad * 8);
      bf16x8 vf1 = *(const bf16x8*)(VTh + (size_t)(t4 * 16 + r16) * Lc + kt + 32 + quad * 8);
      of[t4] = __builtin_amdgcn_mfma_f32_16x16x32_bf16(pf0, vf0, of[t4], 0, 0, 0);
      of[t4] = __builtin_amdgcn_mfma_f32_16x16x32_bf16(pf1, vf1, of[t4], 0, 0, 0);
    }
  }
  // write partials: of rows = quad*4+reg
  #pragma unroll
  for (int reg = 0; reg < 4; reg++) {
    const int l = q0 + quad * 4 + reg;
    const size_t idx = (size_t)s * ROWSc + (size_t)bh * Lc + l;
    #pragma unroll
    for (int t4 = 0; t4 < 4; t4++)
      Op[idx * 64 + t4 * 16 + r16] = of[t4][reg];
  }
  if (lane < 16) {  // this lane's (mi,li) are for query r16 = lane
    const size_t idx = (size_t)s * ROWSc + (size_t)bh * Lc + q0 + lane;
    Mp[idx] = mi;
    Lp[idx] = li;
  }
}

// ---------------- merge partials -> AO ----------------
__global__ __launch_bounds__(256) void k_merge(
    const float* __restrict__ Op, const float* __restrict__ Mp,
    const float* __restrict__ Lp, bf16_t* __restrict__ AO, int nS) {
  const int t = blockIdx.x * 256 + threadIdx.x;
  const int row = t >> 4, dc = (t & 15) * 4;
  float mmax = -1e30f;
  for (int s = 0; s < nS; s++) mmax = fmaxf(mmax, Mp[(size_t)s * ROWSc + row]);
  float L = 0.f;
  float o0 = 0.f, o1 = 0.f, o2 = 0.f, o3 = 0.f;
  for (int s = 0; s < nS; s++) {
    const size_t idx = (size_t)s * ROWSc + row;
    const float w = __expf(Mp[idx] - mmax);
    L += w * Lp[idx];
    const float4 v = *(const float4*)(Op + idx * 64 + dc);
    o0 += w * v.x; o1 += w * v.y; o2 += w * v.z; o3 += w * v.w;
  }
  const float inv = (L > 0.f) ? __builtin_amdgcn_rcpf(L) : 0.f;
  const int bh = row >> 11, l = row & 2047;
  const int b = bh / Hc, h = bh - b * Hc;
  bf16x4 o;
  o[0] = (bf16_t)(o0 * inv); o[1] = (bf16_t)(o1 * inv);
  o[2] = (bf16_t)(o2 * inv); o[3] = (bf16_t)(o3 * inv);
  *(bf16x4*)(AO + ((size_t)(b * Lc + l)) * Ec + h * 64 + dc) = o;
}

// ---------------- launch ----------------

extern "C" void kernel_launch(void* const* d_in, const int* in_sizes, int n_in,
                              void* d_out, int out_size, void* d_ws, size_t ws_size,
                              hipStream_t stream) {
  const float* x    = (const float*)d_in[0];
  const int*   mask = (const int*)d_in[1];
  const float* Wqkv = (const float*)d_in[2];
  const float* bqkv = (const float*)d_in[3];
  const float* Wout = (const float*)d_in[4];
  const float* bout = (const float*)d_in[5];
  float* out = (float*)d_out;

  auto al = [](size_t x) { return (x + 255) & ~(size_t)255; };
  char* ws = (char*)d_ws;
  size_t off = 0;
  auto carve = [&](size_t bytes) -> char* {
    char* p = ws + off;
    off += al(bytes);
    return p;
  };
  bf16_t* WoT = (bf16_t*)carve((size_t)Ec * Ec * 2);
  bf16_t* Qb  = (bf16_t*)carve((size_t)ROWSc * Dc * 2);
  bf16_t* Kb  = (bf16_t*)carve((size_t)ROWSc * Dc * 2);
  bf16_t* VTb = (bf16_t*)carve((size_t)ROWSc * Dc * 2);
  bf16_t* AOb = (bf16_t*)carve((size_t)Mc * Ec * 2);
  float*  qsq = (float*)carve((size_t)ROWSc * 4);
  float*  ksq = (float*)carve((size_t)ROWSc * 4);
  const size_t uni = off;
  bf16_t* xb  = (bf16_t*)(ws + uni);
  bf16_t* WqT = (bf16_t*)(ws + uni + al((size_t)Mc * Ec * 2));
  bf16_t* Vb  = (bf16_t*)(ws + uni + al((size_t)Mc * Ec * 2) + al((size_t)N3c * Ec * 2));
  const size_t ph1 = al((size_t)Mc * Ec * 2) + al((size_t)N3c * Ec * 2) + al((size_t)ROWSc * Dc * 2);
  auto ph2 = [&](int S) {
    return al((size_t)S * ROWSc * Dc * 4) + 2 * al((size_t)S * ROWSc * 4);
  };
  int S = 1;
  {
    size_t need = uni + (ph1 > ph2(2) ? ph1 : ph2(2));
    if (need <= ws_size) S = 2;
  }
  float* Op = (float*)(ws + uni);
  float* Mp = (float*)(ws + uni + al((size_t)S * ROWSc * Dc * 4));
  float* Lp = (float*)(ws + uni + al((size_t)S * ROWSc * Dc * 4) + al((size_t)S * ROWSc * 4));
  (void)in_sizes; (void)n_in; (void)out_size;

  k_cvt<<<(Mc * Ec / 4 + 255) / 256, 256, 0, stream>>>(x, xb, Mc * Ec);
  k_tc<<<dim3(N3c / 32, Ec / 32), dim3(32, 8), 0, stream>>>(Wqkv, WqT, Ec, N3c);
  k_tc<<<dim3(Ec / 32, Ec / 32), dim3(32, 8), 0, stream>>>(Wout, WoT, Ec, Ec);
  k_gemm_qkv<<<dim3(N3c / 128, Mc / 128), 256, 0, stream>>>(xb, WqT, bqkv, Qb, Kb, Vb);
  k_sq<<<ROWSc / 256, 256, 0, stream>>>(Qb, Kb, qsq, ksq);
  k_vt<<<ROWSc / 64, 256, 0, stream>>>(Vb, VTb);
  k_attn<<<dim3(ROWSc / 64, S), 256, 0, stream>>>(Qb, Kb, VTb, qsq, ksq, mask, Op, Mp, Lp, S);
  k_merge<<<ROWSc * 16 / 256, 256, 0, stream>>>(Op, Mp, Lp, AOb, S);
  k_gemm_out<<<dim3(Ec / 128, Mc / 128), 256, 0, stream>>>(AOb, WoT, bout, out);
}

// Round 4
// 219.350 us; speedup vs baseline: 1.6720x; 1.6720x over previous
//
#include <hip/hip_runtime.h>
#include <hip/hip_bf16.h>
#include <cstdint>
#include <cstddef>

// YatAttention on MI355X (gfx950).
// B=2, L=2048, E=768, H=12, D=64. GEMMs in bf16 MFMA 16x16x32 (fp32 accum).
// R4: k_attn restructured as m97-style GEMM loop: async global_load_lds
// double-buffered staging of K/VT tiles (XOR-swizzled for conflict-free
// ds_read_b128), S^T scores + O^T PV so all softmax state is per-lane (query
// = r16); no bpermutes, 2 shuffles per tile.

typedef __bf16 bf16_t;
typedef __bf16 bf16x8 __attribute__((ext_vector_type(8)));
typedef __bf16 bf16x4 __attribute__((ext_vector_type(4)));
typedef float floatx4 __attribute__((ext_vector_type(4)));

#define DEVI static __device__ __forceinline__

#define Bc 2
#define Lc 2048
#define Ec 768
#define Hc 12
#define Dc 64
#define N3c 2304
#define Mc 4096
#define ROWSc (Bc * Hc * Lc)  // 49152

DEVI void glds16(const bf16_t* g, bf16_t* l) {
  __builtin_amdgcn_global_load_lds(
      (const __attribute__((address_space(1))) void*)g,
      (__attribute__((address_space(3))) void*)l, 16, 0, 0);
}

// ---------------- conversion kernels ----------------

__global__ __launch_bounds__(256) void k_cvt(const float* __restrict__ in,
                                             bf16_t* __restrict__ out, int n) {
  int i = (blockIdx.x * 256 + threadIdx.x) * 4;
  if (i >= n) return;
  float4 v = *(const float4*)(in + i);
  bf16x4 o;
  o[0] = (bf16_t)v.x; o[1] = (bf16_t)v.y; o[2] = (bf16_t)v.z; o[3] = (bf16_t)v.w;
  *(bf16x4*)(out + i) = o;
}

__global__ __launch_bounds__(256) void k_tc(const float* __restrict__ in,
                                            bf16_t* __restrict__ out, int R, int C) {
  __shared__ float tile[32][33];
  int c0 = blockIdx.x * 32, r0 = blockIdx.y * 32;
  int tx = threadIdx.x, ty = threadIdx.y;
  #pragma unroll
  for (int i = 0; i < 32; i += 8)
    tile[ty + i][tx] = in[(size_t)(r0 + ty + i) * C + c0 + tx];
  __syncthreads();
  #pragma unroll
  for (int i = 0; i < 32; i += 8)
    out[(size_t)(c0 + ty + i) * R + r0 + tx] = (bf16_t)tile[tx][ty + i];
}

// ---------------- GEMM core (m97 pattern) ----------------

DEVI void gemm_core(const bf16_t* __restrict__ A, const bf16_t* __restrict__ Bt,
                    bf16_t* lA, bf16_t* lB, int m0, int n0, floatx4 (&acc)[4][4]) {
  const int tid = threadIdx.x, wave = tid >> 6, lane = tid & 63;
  const int wm = (wave >> 1) * 64, wn = (wave & 1) * 64;
  const int lrow = lane >> 2, lseg = lane & 3;
  const int quad = lane >> 4, r16 = lane & 15;
  for (int kk = 0; kk < 768; kk += 32) {
    glds16(A  + (size_t)(m0 + wave * 32      + lrow) * 768 + kk + lseg * 8, lA + (wave * 32) * 32);
    glds16(A  + (size_t)(m0 + wave * 32 + 16 + lrow) * 768 + kk + lseg * 8, lA + (wave * 32 + 16) * 32);
    glds16(Bt + (size_t)(n0 + wave * 32      + lrow) * 768 + kk + lseg * 8, lB + (wave * 32) * 32);
    glds16(Bt + (size_t)(n0 + wave * 32 + 16 + lrow) * 768 + kk + lseg * 8, lB + (wave * 32 + 16) * 32);
    __syncthreads();
    bf16x8 af[4], bv[4];
    #pragma unroll
    for (int mi = 0; mi < 4; mi++)
      af[mi] = *(const bf16x8*)(lA + (wm + mi * 16 + r16) * 32 + quad * 8);
    #pragma unroll
    for (int ni = 0; ni < 4; ni++)
      bv[ni] = *(const bf16x8*)(lB + (wn + ni * 16 + r16) * 32 + quad * 8);
    #pragma unroll
    for (int mi = 0; mi < 4; mi++)
      #pragma unroll
      for (int ni = 0; ni < 4; ni++)
        acc[mi][ni] = __builtin_amdgcn_mfma_f32_16x16x32_bf16(af[mi], bv[ni], acc[mi][ni], 0, 0, 0);
    __syncthreads();
  }
}

__global__ __launch_bounds__(256) void k_gemm_qkv(
    const bf16_t* __restrict__ A, const bf16_t* __restrict__ Bt,
    const float* __restrict__ bias,
    bf16_t* __restrict__ Qo, bf16_t* __restrict__ Ko, bf16_t* __restrict__ Vo) {
  __shared__ bf16_t lA[128 * 32];
  __shared__ bf16_t lB[128 * 32];
  const int m0 = blockIdx.y * 128, n0 = blockIdx.x * 128;
  const int tid = threadIdx.x, wave = tid >> 6, lane = tid & 63;
  const int wm = (wave >> 1) * 64, wn = (wave & 1) * 64;
  const int quad = lane >> 4, r16 = lane & 15;
  floatx4 acc[4][4] = {};
  gemm_core(A, Bt, lA, lB, m0, n0, acc);

  const int sec = n0 / 768;
  bf16_t* dst = (sec == 0) ? Qo : ((sec == 1) ? Ko : Vo);
  #pragma unroll
  for (int ni = 0; ni < 4; ni++) {
    const int n = n0 + wn + ni * 16 + r16;
    const int nn = n - sec * 768;
    const int h = nn >> 6, d = nn & 63;
    const float bvs = bias[n];
    #pragma unroll
    for (int mi = 0; mi < 4; mi++) {
      #pragma unroll
      for (int reg = 0; reg < 4; reg++) {
        const int m = m0 + wm + mi * 16 + quad * 4 + reg;
        const int b = m >> 11, l = m & 2047;
        const float v = acc[mi][ni][reg] + bvs;
        dst[(((size_t)(b * Hc + h)) * Lc + l) * Dc + d] = (bf16_t)v;
      }
    }
  }
}

__global__ __launch_bounds__(256) void k_gemm_out(
    const bf16_t* __restrict__ A, const bf16_t* __restrict__ Bt,
    const float* __restrict__ bias, float* __restrict__ out) {
  __shared__ bf16_t lA[128 * 32];
  __shared__ bf16_t lB[128 * 32];
  const int m0 = blockIdx.y * 128, n0 = blockIdx.x * 128;
  const int tid = threadIdx.x, wave = tid >> 6, lane = tid & 63;
  const int wm = (wave >> 1) * 64, wn = (wave & 1) * 64;
  const int quad = lane >> 4, r16 = lane & 15;
  floatx4 acc[4][4] = {};
  gemm_core(A, Bt, lA, lB, m0, n0, acc);
  #pragma unroll
  for (int ni = 0; ni < 4; ni++) {
    const int n = n0 + wn + ni * 16 + r16;
    const float bvs = bias[n];
    #pragma unroll
    for (int mi = 0; mi < 4; mi++) {
      #pragma unroll
      for (int reg = 0; reg < 4; reg++) {
        const int m = m0 + wm + mi * 16 + quad * 4 + reg;
        out[(size_t)m * Ec + n] = acc[mi][ni][reg] + bvs;
      }
    }
  }
}

// ---------------- q_sq / k_sq (ksq carries +eps) ----------------
__global__ __launch_bounds__(256) void k_sq(const bf16_t* __restrict__ Q,
                                            const bf16_t* __restrict__ K,
                                            float* __restrict__ qsq, float* __restrict__ ksq) {
  const int row = blockIdx.x * 256 + threadIdx.x;
  const bf16x8* q = (const bf16x8*)(Q + (size_t)row * 64);
  const bf16x8* k = (const bf16x8*)(K + (size_t)row * 64);
  float sq = 0.f, sk = 0.f;
  #pragma unroll
  for (int c = 0; c < 8; c++) {
    bf16x8 vq = q[c], vk = k[c];
    #pragma unroll
    for (int j = 0; j < 8; j++) {
      float a = (float)vq[j]; sq += a * a;
      float b = (float)vk[j]; sk += b * b;
    }
  }
  qsq[row] = sq;
  ksq[row] = sk + 1e-6f;
}

// ---------------- V transpose ----------------
__global__ __launch_bounds__(256) void k_vt(const bf16_t* __restrict__ V,
                                            bf16_t* __restrict__ VT) {
  __shared__ bf16_t t[64][72];
  const int gid = blockIdx.x;
  const int bh = gid >> 5, j0 = (gid & 31) * 64;
  const int tid = threadIdx.x;
  const bf16_t* Vh = V + ((size_t)bh * Lc) * Dc;
  bf16_t* VTh = VT + ((size_t)bh * Dc) * Lc;
  #pragma unroll
  for (int it = 0; it < 2; ++it) {
    int c = tid + it * 256;
    int j = c >> 3, seg = c & 7;
    *(bf16x8*)&t[j][seg * 8] = *(const bf16x8*)(Vh + (size_t)(j0 + j) * 64 + seg * 8);
  }
  __syncthreads();
  #pragma unroll
  for (int it = 0; it < 2; ++it) {
    int c = tid + it * 256;
    int d = c >> 3, jseg = c & 7;
    bf16x8 o;
    #pragma unroll
    for (int u = 0; u < 8; u++) o[u] = t[jseg * 8 + u][d];
    *(bf16x8*)(VTh + (size_t)d * Lc + j0 + jseg * 8) = o;
  }
}

// ---------------- flash attention: LDS-staged, double-buffered ----------------
// grid = (768, S). Block: 4 waves, 64 queries (wave = 16). Key tile = 64.
// K tile + VT tile staged in LDS via global_load_lds, XOR-swizzled chunks.
// S^T = K.Q^T scores; O^T = VT.P^T accum -> softmax state per-lane (q=r16).
__global__ __launch_bounds__(256) void k_attn(
    const bf16_t* __restrict__ Q, const bf16_t* __restrict__ K,
    const bf16_t* __restrict__ VT, const float* __restrict__ qsq,
    const float* __restrict__ ksq, const int* __restrict__ mask,
    float* __restrict__ Op, float* __restrict__ Mp, float* __restrict__ Lp,
    int nS) {
  __shared__ bf16_t lK[2][4096];   // 64 keys x 64 d, swizzled 16B chunks
  __shared__ bf16_t lV[2][4096];   // 64 d x 64 keys, swizzled 16B chunks
  __shared__ bf16_t lP[4][16 * 72];
  const int gid = blockIdx.x;
  const int s = blockIdx.y;
  const int bh = gid >> 5, qt = gid & 31;
  const int b = bh / Hc;
  const int tid = threadIdx.x, wave = tid >> 6, lane = tid & 63;
  const int quad = lane >> 4, r16 = lane & 15;
  const int q0 = qt * 64 + wave * 16;
  const bf16_t* Qh = Q + ((size_t)bh * Lc) * Dc;
  const bf16_t* Kh = K + ((size_t)bh * Lc) * Dc;
  const bf16_t* VTh = VT + ((size_t)bh * Dc) * Lc;
  const float* qsqh = qsq + bh * Lc;
  const float* ksqh = ksq + bh * Lc;
  const int* maskb = mask + b * Lc;
  bf16_t* myP = &lP[wave][0];

  const int kt_lo = (32 * s) / nS * 64;
  const int kt_hi = (32 * (s + 1)) / nS * 64;
  const int nt = (kt_hi - kt_lo) >> 6;

  // --- staging geometry: chunk p = i*256 + wave*64 + lane covers row p>>3,
  // slot p&7 which holds global chunk (p&7)^((p>>3)&7).
  const int p0 = wave * 64 + lane;         // inst 0; inst 1 = p0 + 256 (row+32)
  const int srow = p0 >> 3;                // 0..31
  const int sj = (p0 & 7) ^ (srow & 7);    // swizzled global chunk
  const bf16_t* kg0 = Kh + (size_t)(kt_lo + srow) * 64 + sj * 8;
  const bf16_t* kg1 = kg0 + 32 * 64;
  const bf16_t* vg0 = VTh + (size_t)srow * Lc + kt_lo + sj * 8;
  const bf16_t* vg1 = vg0 + 32 * Lc;
  // LDS dests (wave-uniform): chunk base (i*256 + wave*64)*8 elements
  const int ld0 = wave * 64 * 8, ld1 = (256 + wave * 64) * 8;

  // fragment read offsets (swizzled slots), elements
  const int sl0 = ((quad ^ (r16 & 7)) * 8);
  const int sl1 = sl0 ^ 32;  // chunk quad+4

  // Q B-fragments + per-lane query state
  bf16x8 qf0 = *(const bf16x8*)(Qh + (size_t)(q0 + r16) * 64 + quad * 8);
  bf16x8 qf1 = *(const bf16x8*)(Qh + (size_t)(q0 + r16) * 64 + 32 + quad * 8);
  const float qs = qsqh[q0 + r16];
  float mi = -1e30f, li = 0.f;
  floatx4 of[4] = {};  // O^T: lane holds O^T[d=t4*16+quad*4+reg][q=r16]

  // prologue: stage tile 0 into buf 0
  glds16(kg0, &lK[0][ld0]);
  glds16(kg1, &lK[0][ld1]);
  glds16(vg0, &lV[0][ld0]);
  glds16(vg1, &lV[0][ld1]);
  kg0 += 4096; kg1 += 4096; vg0 += 64; vg1 += 64;
  __syncthreads();

  for (int t = 0; t < nt; t++) {
    const int cur = t & 1;
    if (t + 1 < nt) {
      const int nxt = cur ^ 1;
      glds16(kg0, &lK[nxt][ld0]);
      glds16(kg1, &lK[nxt][ld1]);
      glds16(vg0, &lV[nxt][ld0]);
      glds16(vg1, &lV[nxt][ld1]);
      kg0 += 4096; kg1 += 4096; vg0 += 64; vg1 += 64;
    }
    const int kt = kt_lo + t * 64;
    // ksq/mask for this lane's 16 keys (c*16 + quad*4 + reg)
    float4 ks4[4];
    int4 mk4[4];
    #pragma unroll
    for (int c = 0; c < 4; c++) {
      ks4[c] = *(const float4*)(ksqh + kt + c * 16 + quad * 4);
      mk4[c] = *(const int4*)(maskb + kt + c * 16 + quad * 4);
    }
    // S^T MFMAs from LDS K tile
    floatx4 dot[4];
    #pragma unroll
    for (int c = 0; c < 4; c++) {
      const int rbase = (c * 16 + r16) * 64;
      bf16x8 kf0 = *(const bf16x8*)(&lK[cur][rbase + sl0]);
      bf16x8 kf1 = *(const bf16x8*)(&lK[cur][rbase + sl1]);
      floatx4 a = {};
      a = __builtin_amdgcn_mfma_f32_16x16x32_bf16(kf0, qf0, a, 0, 0, 0);
      a = __builtin_amdgcn_mfma_f32_16x16x32_bf16(kf1, qf1, a, 0, 0, 0);
      dot[c] = a;
    }
    // transform + online softmax (lane owns 16 scores of query r16)
    float sv[4][4];
    float rmax = -1e30f;
    #pragma unroll
    for (int c = 0; c < 4; c++) {
      #pragma unroll
      for (int reg = 0; reg < 4; reg++) {
        const float dd = dot[c][reg];
        const float kss = ((const float*)&ks4[c])[reg];  // has +eps
        const int mk = ((const int*)&mk4[c])[reg];
        const float den = qs + kss - 2.f * dd;
        float sc = dd * dd * __builtin_amdgcn_rcpf(den);
        sc = (mk == 1) ? sc : -1e30f;
        sv[c][reg] = sc;
        rmax = fmaxf(rmax, sc);
      }
    }
    rmax = fmaxf(rmax, __shfl_xor(rmax, 16));
    rmax = fmaxf(rmax, __shfl_xor(rmax, 32));
    const float mnew = fmaxf(mi, rmax);
    const float alpha = __expf(mi - mnew);
    float psum = 0.f;
    #pragma unroll
    for (int c = 0; c < 4; c++) {
      bf16x4 pk;
      #pragma unroll
      for (int reg = 0; reg < 4; reg++) {
        const float p = __expf(sv[c][reg] - mnew);  // masked: exp(-huge)=0
        psum += p;
        pk[reg] = (bf16_t)p;
      }
      *(bf16x4*)(myP + r16 * 72 + c * 16 + quad * 4) = pk;
    }
    psum += __shfl_xor(psum, 16);
    psum += __shfl_xor(psum, 32);
    li = li * alpha + psum;
    mi = mnew;
    #pragma unroll
    for (int t4 = 0; t4 < 4; t4++) {
      #pragma unroll
      for (int reg = 0; reg < 4; reg++) of[t4][reg] *= alpha;
    }
    // O^T += VT . P^T : A = VT frag (m=d), B = P frag (n=query)
    bf16x8 pf0 = *(const bf16x8*)(myP + r16 * 72 + quad * 8);
    bf16x8 pf1 = *(const bf16x8*)(myP + r16 * 72 + 32 + quad * 8);
    #pragma unroll
    for (int t4 = 0; t4 < 4; t4++) {
      const int rbase = (t4 * 16 + r16) * 64;
      bf16x8 vf0 = *(const bf16x8*)(&lV[cur][rbase + sl0]);
      bf16x8 vf1 = *(const bf16x8*)(&lV[cur][rbase + sl1]);
      of[t4] = __builtin_amdgcn_mfma_f32_16x16x32_bf16(vf0, pf0, of[t4], 0, 0, 0);
      of[t4] = __builtin_amdgcn_mfma_f32_16x16x32_bf16(vf1, pf1, of[t4], 0, 0, 0);
    }
    __syncthreads();
  }
  // epilogue: lane writes O^T[d][q=r16] -> Op[idx(q)*64 + d], d = t4*16+quad*4+reg
  const size_t idx = (size_t)s * ROWSc + (size_t)bh * Lc + q0 + r16;
  #pragma unroll
  for (int t4 = 0; t4 < 4; t4++)
    *(float4*)(Op + idx * 64 + t4 * 16 + quad * 4) =
        make_float4(of[t4][0], of[t4][1], of[t4][2], of[t4][3]);
  if (lane < 16) { Mp[idx] = mi; Lp[idx] = li; }
}

// ---------------- merge partials -> AO ----------------
__global__ __launch_bounds__(256) void k_merge(
    const float* __restrict__ Op, const float* __restrict__ Mp,
    const float* __restrict__ Lp, bf16_t* __restrict__ AO, int nS) {
  const int t = blockIdx.x * 256 + threadIdx.x;
  const int row = t >> 4, dc = (t & 15) * 4;
  float mmax = -1e30f;
  for (int s = 0; s < nS; s++) mmax = fmaxf(mmax, Mp[(size_t)s * ROWSc + row]);
  float L = 0.f;
  float o0 = 0.f, o1 = 0.f, o2 = 0.f, o3 = 0.f;
  for (int s = 0; s < nS; s++) {
    const size_t idx = (size_t)s * ROWSc + row;
    const float w = __expf(Mp[idx] - mmax);
    L += w * Lp[idx];
    const float4 v = *(const float4*)(Op + idx * 64 + dc);
    o0 += w * v.x; o1 += w * v.y; o2 += w * v.z; o3 += w * v.w;
  }
  const float inv = (L > 0.f) ? __builtin_amdgcn_rcpf(L) : 0.f;
  const int bh = row >> 11, l = row & 2047;
  const int b = bh / Hc, h = bh - b * Hc;
  bf16x4 o;
  o[0] = (bf16_t)(o0 * inv); o[1] = (bf16_t)(o1 * inv);
  o[2] = (bf16_t)(o2 * inv); o[3] = (bf16_t)(o3 * inv);
  *(bf16x4*)(AO + ((size_t)(b * Lc + l)) * Ec + h * 64 + dc) = o;
}

// ---------------- launch ----------------

extern "C" void kernel_launch(void* const* d_in, const int* in_sizes, int n_in,
                              void* d_out, int out_size, void* d_ws, size_t ws_size,
                              hipStream_t stream) {
  const float* x    = (const float*)d_in[0];
  const int*   mask = (const int*)d_in[1];
  const float* Wqkv = (const float*)d_in[2];
  const float* bqkv = (const float*)d_in[3];
  const float* Wout = (const float*)d_in[4];
  const float* bout = (const float*)d_in[5];
  float* out = (float*)d_out;

  auto al = [](size_t x) { return (x + 255) & ~(size_t)255; };
  char* ws = (char*)d_ws;
  size_t off = 0;
  auto carve = [&](size_t bytes) -> char* {
    char* p = ws + off;
    off += al(bytes);
    return p;
  };
  bf16_t* WoT = (bf16_t*)carve((size_t)Ec * Ec * 2);
  bf16_t* Qb  = (bf16_t*)carve((size_t)ROWSc * Dc * 2);
  bf16_t* Kb  = (bf16_t*)carve((size_t)ROWSc * Dc * 2);
  bf16_t* VTb = (bf16_t*)carve((size_t)ROWSc * Dc * 2);
  bf16_t* AOb = (bf16_t*)carve((size_t)Mc * Ec * 2);
  float*  qsq = (float*)carve((size_t)ROWSc * 4);
  float*  ksq = (float*)carve((size_t)ROWSc * 4);
  const size_t uni = off;
  bf16_t* xb  = (bf16_t*)(ws + uni);
  bf16_t* WqT = (bf16_t*)(ws + uni + al((size_t)Mc * Ec * 2));
  bf16_t* Vb  = (bf16_t*)(ws + uni + al((size_t)Mc * Ec * 2) + al((size_t)N3c * Ec * 2));
  const size_t ph1 = al((size_t)Mc * Ec * 2) + al((size_t)N3c * Ec * 2) + al((size_t)ROWSc * Dc * 2);
  auto ph2 = [&](int S) {
    return al((size_t)S * ROWSc * Dc * 4) + 2 * al((size_t)S * ROWSc * 4);
  };
  int S = 1;
  {
    size_t need = uni + (ph1 > ph2(2) ? ph1 : ph2(2));
    if (need <= ws_size) S = 2;
  }
  float* Op = (float*)(ws + uni);
  float* Mp = (float*)(ws + uni + al((size_t)S * ROWSc * Dc * 4));
  float* Lp = (float*)(ws + uni + al((size_t)S * ROWSc * Dc * 4) + al((size_t)S * ROWSc * 4));
  (void)in_sizes; (void)n_in; (void)out_size;

  k_cvt<<<(Mc * Ec / 4 + 255) / 256, 256, 0, stream>>>(x, xb, Mc * Ec);
  k_tc<<<dim3(N3c / 32, Ec / 32), dim3(32, 8), 0, stream>>>(Wqkv, WqT, Ec, N3c);
  k_tc<<<dim3(Ec / 32, Ec / 32), dim3(32, 8), 0, stream>>>(Wout, WoT, Ec, Ec);
  k_gemm_qkv<<<dim3(N3c / 128, Mc / 128), 256, 0, stream>>>(xb, WqT, bqkv, Qb, Kb, Vb);
  k_sq<<<ROWSc / 256, 256, 0, stream>>>(Qb, Kb, qsq, ksq);
  k_vt<<<ROWSc / 64, 256, 0, stream>>>(Vb, VTb);
  k_attn<<<dim3(ROWSc / 64, S), 256, 0, stream>>>(Qb, Kb, VTb, qsq, ksq, mask, Op, Mp, Lp, S);
  k_merge<<<ROWSc * 16 / 256, 256, 0, stream>>>(Op, Mp, Lp, AOb, S);
  k_gemm_out<<<dim3(Ec / 128, Mc / 128), 256, 0, stream>>>(AOb, WoT, bout, out);
}